// Round 11
// baseline (150.642 us; speedup 1.0000x reference)
//
#include <hip/hip_runtime.h>

#define G16 16
#define CHW 200704            // C*H*W = 64*56*56
#define J4 (CHW / 4)          // 50176 float4 chunks per (n,g) slab
#define NBATCH 16             // N
#define NCHUNK (NBATCH * J4)  // 802816 total float4 chunks
#define NPAIR 136             // 16*17/2 triangular Gram entries
#define NVAL (NPAIR + G16)    // 152 reduced values
#define NPOSBLK 784           // position-blocks per batch slab: 784*64 == J4
#define NTILES (NBATCH * NPOSBLK)  // 12544 (n, posblk) tiles
#define NBLK_MAX 1280         // 5 blocks/CU * 256 CU — full residency @ LB(256,5)
#define M_ELEMS 3211264.0f    // N*C*H*W
#define EPSV 1e-5f

using f4 = __attribute__((ext_vector_type(4))) float;

__device__ __forceinline__ float dot4(const f4 a, const f4 b, float acc) {
    return fmaf(a.x, b.x, fmaf(a.y, b.y, fmaf(a.z, b.z, fmaf(a.w, b.w, acc))));
}
__device__ __forceinline__ float wred(float v) {
#pragma unroll
    for (int o = 32; o > 0; o >>= 1) v += __shfl_xor(v, o, 64);
    return v;
}

// Pass 1: pair-split Gram, grid-stride over (n, posblk) tiles, 5 blocks/CU
// (A/B vs R10's 4/CU: gram is latency-exposed at 16 waves/CU; 20 waves
// hides ~25% more. VGPR budget 512/5=102; paths estimated ~90-100).
//  wave0: tri pairs within groups 0..7  (36) + sums 0..7
//  wave1: tri pairs within groups 8..15 (36) + sums 8..15
//  wave2: rect pairs g1 in 8..15 x g2 in 0..3 (32)
//  wave3: rect pairs g1 in 8..15 x g2 in 4..7 (32)
__global__ __launch_bounds__(256, 5) void gram_k(const float* __restrict__ x,
                                                 float* __restrict__ partials,
                                                 int nblk) {
    const int lane = threadIdx.x & 63;
    const int wv = threadIdx.x >> 6;
    __shared__ float red[NVAL];

    if (wv < 2) {
        const int GB = wv * 8;
        float acc[36], sums[8];
#pragma unroll
        for (int i = 0; i < 36; ++i) acc[i] = 0.f;
#pragma unroll
        for (int g = 0; g < 8; ++g) sums[g] = 0.f;
#pragma unroll 1
        for (int t = blockIdx.x; t < NTILES; t += nblk) {
            const int n = t / NPOSBLK;
            const int pb = t - n * NPOSBLK;
            const float* bp = x + (size_t)n * (G16 * CHW) + (size_t)(pb * 64 + lane) * 4;
            f4 v[8];
#pragma unroll
            for (int g = 0; g < 8; ++g)
                v[g] = *reinterpret_cast<const f4*>(bp + (size_t)(GB + g) * CHW);
#pragma unroll
            for (int g1 = 0; g1 < 8; ++g1) {
                sums[g1] += (v[g1].x + v[g1].y) + (v[g1].z + v[g1].w);
#pragma unroll
                for (int g2 = 0; g2 <= g1; ++g2)
                    acc[g1 * (g1 + 1) / 2 + g2] =
                        dot4(v[g1], v[g2], acc[g1 * (g1 + 1) / 2 + g2]);
            }
        }
#pragma unroll
        for (int g1 = 0; g1 < 8; ++g1)
#pragma unroll
            for (int g2 = 0; g2 <= g1; ++g2) {
                const float s = wred(acc[g1 * (g1 + 1) / 2 + g2]);
                if (lane == 0) {
                    const int G1 = GB + g1, G2 = GB + g2;
                    red[G1 * (G1 + 1) / 2 + G2] = s;
                }
            }
#pragma unroll
        for (int g = 0; g < 8; ++g) {
            const float s = wred(sums[g]);
            if (lane == 0) red[NPAIR + GB + g] = s;
        }
    } else {
        const int G2B = (wv - 2) * 4;
        float acc[32];
#pragma unroll
        for (int i = 0; i < 32; ++i) acc[i] = 0.f;
#pragma unroll 1
        for (int t = blockIdx.x; t < NTILES; t += nblk) {
            const int n = t / NPOSBLK;
            const int pb = t - n * NPOSBLK;
            const float* bp = x + (size_t)n * (G16 * CHW) + (size_t)(pb * 64 + lane) * 4;
            f4 v2[4];
#pragma unroll
            for (int b = 0; b < 4; ++b)
                v2[b] = *reinterpret_cast<const f4*>(bp + (size_t)(G2B + b) * CHW);
            // split the 8 g1-rows into two halves to cap live registers
            f4 v1[4];
#pragma unroll
            for (int a = 0; a < 4; ++a)
                v1[a] = *reinterpret_cast<const f4*>(bp + (size_t)(8 + a) * CHW);
#pragma unroll
            for (int a = 0; a < 4; ++a)
#pragma unroll
                for (int b = 0; b < 4; ++b)
                    acc[a * 4 + b] = dot4(v1[a], v2[b], acc[a * 4 + b]);
#pragma unroll
            for (int a = 0; a < 4; ++a)
                v1[a] = *reinterpret_cast<const f4*>(bp + (size_t)(12 + a) * CHW);
#pragma unroll
            for (int a = 0; a < 4; ++a)
#pragma unroll
                for (int b = 0; b < 4; ++b)
                    acc[(4 + a) * 4 + b] = dot4(v1[a], v2[b], acc[(4 + a) * 4 + b]);
        }
#pragma unroll
        for (int a = 0; a < 8; ++a)
#pragma unroll
            for (int b = 0; b < 4; ++b) {
                const float s = wred(acc[a * 4 + b]);
                if (lane == 0) {
                    const int G1 = 8 + a, G2 = G2B + b;
                    red[G1 * (G1 + 1) / 2 + G2] = s;
                }
            }
    }
    __syncthreads();
    if (threadIdx.x < NVAL)
        partials[(size_t)threadIdx.x * nblk + blockIdx.x] = red[threadIdx.x];
}

// Shared solve tail: wave-parallel Cholesky + L^{-1} from sm[NVAL] (wave 0).
__device__ __forceinline__ void solve_tail(const float* sm, float* wm, int lane) {
    const float inv_m = 1.0f / M_ELEMS;
    const int i = lane;
    const float mu_i = (i < G16) ? sm[NPAIR + i] * inv_m : 0.f;

    float di = 0.f;
    if (i < G16) di = sm[i * (i + 1) / 2 + i] * inv_m - mu_i * mu_i + EPSV;
    float tr = di;
#pragma unroll
    for (int o = 32; o > 0; o >>= 1) tr += __shfl_xor(tr, o, 64);
    const float rtr = 1.0f / tr;

    float A[G16];
#pragma unroll
    for (int j = 0; j < G16; ++j) {
        const float mu_j = sm[NPAIR + j] * inv_m;
        const int idx = (i >= j) ? (i * (i + 1) / 2 + j) : (j * (j + 1) / 2 + i);
        float v = (i < G16) ? sm[idx] * inv_m : 0.f;
        v = v - mu_i * mu_j + ((i == j) ? EPSV : 0.f);
        A[j] = v * rtr;
    }

    float Lr[G16];
    float dinv = 0.f;
#pragma unroll
    for (int j = 0; j < G16; ++j) {
        float s = A[j];
#pragma unroll
        for (int k = 0; k < j; ++k)
            s -= Lr[k] * __shfl(Lr[k], j, 64);
        const float djj = __shfl(s, j, 64);
        const float d = sqrtf(djj);
        const float inv = 1.0f / d;
        float lij = (i == j) ? d : s * inv;
        if (i < j) lij = 0.f;
        Lr[j] = lij;
        if (i == j) dinv = inv;
    }

    float Wc[G16];
#pragma unroll
    for (int r = 0; r < G16; ++r) {
        float s = (lane == r) ? 1.f : 0.f;
#pragma unroll
        for (int k = 0; k < r; ++k)
            s -= __shfl(Lr[k], r, 64) * Wc[k];
        Wc[r] = s * __shfl(dinv, r, 64);
    }
    if (lane < G16) {
#pragma unroll
        for (int r = 0; r < G16; ++r)
            wm[r * G16 + lane] = Wc[r];
    }
}

// Pass 2 (one block, 1024 thr): unrolled reduce — compile-time NB, each
// value's 1280-wide row read as 5 independent float4 loads per lane.
__global__ __launch_bounds__(1024) void solve_k_fast(const float* __restrict__ partials,
                                                     float* __restrict__ wm) {
    __shared__ float sm[NVAL];
    const int lane = threadIdx.x & 63;
    const int wave = threadIdx.x >> 6;
#pragma unroll 1
    for (int v = wave; v < NVAL; v += 16) {
        const float* row = partials + (size_t)v * NBLK_MAX;
        f4 a4 = {0.f, 0.f, 0.f, 0.f};
#pragma unroll
        for (int b = 0; b < NBLK_MAX / 256; ++b) {   // 5 independent 16B loads
            const f4 p = *reinterpret_cast<const f4*>(row + b * 256 + lane * 4);
            a4.x += p.x; a4.y += p.y; a4.z += p.z; a4.w += p.w;
        }
        float a = (a4.x + a4.y) + (a4.z + a4.w);
        a = wred(a);
        if (lane == 0) sm[v] = a;
    }
    __syncthreads();
    if (wave != 0) return;
    solve_tail(sm, wm, lane);
}

// Generic fallback (runtime nblk) — only used if ws can't fit 1280 partials.
__global__ __launch_bounds__(1024) void solve_k_gen(const float* __restrict__ partials,
                                                    int nblk, float* __restrict__ wm) {
    __shared__ float sm[NVAL];
    const int lane = threadIdx.x & 63;
    const int wave = threadIdx.x >> 6;
    for (int v = wave; v < NVAL; v += 16) {
        float a = 0.f;
        for (int b = lane; b < nblk; b += 64)
            a += partials[(size_t)v * nblk + b];
        a = wred(a);
        if (lane == 0) sm[v] = a;
    }
    __syncthreads();
    if (wave != 0) return;
    solve_tail(sm, wm, lane);
}

// Pass 3: out[g,:] = sum_{g2<=g} wm[g][g2] * x[g2,:]
// R10 config (best known): plain loads, NT stores, one chunk per thread.
// Apply sits within ~8% of the m13 copy ceiling (410 MB mixed stream).
__global__ __launch_bounds__(256, 4) void apply_k(const float* __restrict__ x,
                                                  const float* __restrict__ wm,
                                                  float* __restrict__ out) {
    __shared__ float w[G16 * G16];
    if (threadIdx.x < G16 * G16) w[threadIdx.x] = wm[threadIdx.x];
    __syncthreads();
    const int c = blockIdx.x * 256 + threadIdx.x;
    const int n = c / J4;
    const int j4 = c - n * J4;
    const size_t base = (size_t)n * (G16 * CHW) + (size_t)j4 * 4;
    f4 v[G16];
#pragma unroll
    for (int g = 0; g < G16; ++g)
        v[g] = *reinterpret_cast<const f4*>(x + base + (size_t)g * CHW);
#pragma unroll
    for (int g = 0; g < G16; ++g) {
        f4 o = {0.f, 0.f, 0.f, 0.f};
#pragma unroll
        for (int g2 = 0; g2 <= g; ++g2) {
            const float wv = w[g * G16 + g2];
            o.x = fmaf(wv, v[g2].x, o.x);
            o.y = fmaf(wv, v[g2].y, o.y);
            o.z = fmaf(wv, v[g2].z, o.z);
            o.w = fmaf(wv, v[g2].w, o.w);
        }
        __builtin_nontemporal_store(o, reinterpret_cast<f4*>(out + base + (size_t)g * CHW));
    }
}

extern "C" void kernel_launch(void* const* d_in, const int* in_sizes, int n_in,
                              void* d_out, int out_size, void* d_ws, size_t ws_size,
                              hipStream_t stream) {
    const float* x = (const float*)d_in[0];
    float* out = (float*)d_out;
    float* wm = (float*)d_ws;                 // first 256 floats
    float* partials = (float*)d_ws + 256;     // NVAL * nblk floats

    int nblk = NBLK_MAX;
    const size_t avail = (ws_size / 4 > 256) ? ((ws_size / 4 - 256) / NVAL) : 1;
    if ((size_t)nblk > avail) nblk = (int)avail;
    if (nblk < 1) nblk = 1;

    gram_k<<<nblk, 256, 0, stream>>>(x, partials, nblk);
    if (nblk == NBLK_MAX)
        solve_k_fast<<<1, 1024, 0, stream>>>(partials, wm);
    else
        solve_k_gen<<<1, 1024, 0, stream>>>(partials, nblk, wm);
    apply_k<<<NCHUNK / 256, 256, 0, stream>>>(x, wm, out);
}

// Round 12
// 118.217 us; speedup vs baseline: 1.2743x; 1.2743x over previous
//
#include <hip/hip_runtime.h>

#define G16 16
#define CHW 200704            // C*H*W = 64*56*56
#define J4 (CHW / 4)          // 50176 float4 chunks per (n,g) slab
#define NBATCH 16             // N
#define NCHUNK (NBATCH * J4)  // 802816 total float4 chunks
#define NPAIR 136             // 16*17/2 triangular Gram entries
#define NVAL (NPAIR + G16)    // 152 reduced values
#define NPOSBLK 784           // position-blocks per batch slab: 784*64 == J4
#define NTILES (NBATCH * NPOSBLK)  // 12544 (n, posblk) tiles
#define NBLK_MAX 1024         // 4 blocks/CU * 256 CU — full residency
#define M_ELEMS 3211264.0f    // N*C*H*W
#define EPSV 1e-5f

using f4 = __attribute__((ext_vector_type(4))) float;

__device__ __forceinline__ float dot4(const f4 a, const f4 b, float acc) {
    return fmaf(a.x, b.x, fmaf(a.y, b.y, fmaf(a.z, b.z, fmaf(a.w, b.w, acc))));
}
__device__ __forceinline__ float wred(float v) {
#pragma unroll
    for (int o = 32; o > 0; o >>= 1) v += __shfl_xor(v, o, 64);
    return v;
}

// Pass 1: pair-split Gram, grid-stride over (n, posblk) tiles, 4 blocks/CU.
// (R10 config — LB(256,5)/nblk=1280 spilled and cost +32 µs, R11.)
//  wave0: tri pairs within groups 0..7  (36) + sums 0..7
//  wave1: tri pairs within groups 8..15 (36) + sums 8..15
//  wave2: rect pairs g1 in 8..15 x g2 in 0..3 (32)
//  wave3: rect pairs g1 in 8..15 x g2 in 4..7 (32)
__global__ __launch_bounds__(256, 4) void gram_k(const float* __restrict__ x,
                                                 float* __restrict__ partials,
                                                 int nblk) {
    const int lane = threadIdx.x & 63;
    const int wv = threadIdx.x >> 6;
    __shared__ float red[NVAL];

    if (wv < 2) {
        const int GB = wv * 8;
        float acc[36], sums[8];
#pragma unroll
        for (int i = 0; i < 36; ++i) acc[i] = 0.f;
#pragma unroll
        for (int g = 0; g < 8; ++g) sums[g] = 0.f;
#pragma unroll 1
        for (int t = blockIdx.x; t < NTILES; t += nblk) {
            const int n = t / NPOSBLK;
            const int pb = t - n * NPOSBLK;
            const float* bp = x + (size_t)n * (G16 * CHW) + (size_t)(pb * 64 + lane) * 4;
            f4 v[8];
#pragma unroll
            for (int g = 0; g < 8; ++g)
                v[g] = *reinterpret_cast<const f4*>(bp + (size_t)(GB + g) * CHW);
#pragma unroll
            for (int g1 = 0; g1 < 8; ++g1) {
                sums[g1] += (v[g1].x + v[g1].y) + (v[g1].z + v[g1].w);
#pragma unroll
                for (int g2 = 0; g2 <= g1; ++g2)
                    acc[g1 * (g1 + 1) / 2 + g2] =
                        dot4(v[g1], v[g2], acc[g1 * (g1 + 1) / 2 + g2]);
            }
        }
#pragma unroll
        for (int g1 = 0; g1 < 8; ++g1)
#pragma unroll
            for (int g2 = 0; g2 <= g1; ++g2) {
                const float s = wred(acc[g1 * (g1 + 1) / 2 + g2]);
                if (lane == 0) {
                    const int G1 = GB + g1, G2 = GB + g2;
                    red[G1 * (G1 + 1) / 2 + G2] = s;
                }
            }
#pragma unroll
        for (int g = 0; g < 8; ++g) {
            const float s = wred(sums[g]);
            if (lane == 0) red[NPAIR + GB + g] = s;
        }
    } else {
        const int G2B = (wv - 2) * 4;
        float acc[32];
#pragma unroll
        for (int i = 0; i < 32; ++i) acc[i] = 0.f;
#pragma unroll 1
        for (int t = blockIdx.x; t < NTILES; t += nblk) {
            const int n = t / NPOSBLK;
            const int pb = t - n * NPOSBLK;
            const float* bp = x + (size_t)n * (G16 * CHW) + (size_t)(pb * 64 + lane) * 4;
            f4 v1[8], v2[4];
#pragma unroll
            for (int a = 0; a < 8; ++a)
                v1[a] = *reinterpret_cast<const f4*>(bp + (size_t)(8 + a) * CHW);
#pragma unroll
            for (int b = 0; b < 4; ++b)
                v2[b] = *reinterpret_cast<const f4*>(bp + (size_t)(G2B + b) * CHW);
#pragma unroll
            for (int a = 0; a < 8; ++a)
#pragma unroll
                for (int b = 0; b < 4; ++b)
                    acc[a * 4 + b] = dot4(v1[a], v2[b], acc[a * 4 + b]);
        }
#pragma unroll
        for (int a = 0; a < 8; ++a)
#pragma unroll
            for (int b = 0; b < 4; ++b) {
                const float s = wred(acc[a * 4 + b]);
                if (lane == 0) {
                    const int G1 = 8 + a, G2 = G2B + b;
                    red[G1 * (G1 + 1) / 2 + G2] = s;
                }
            }
    }
    __syncthreads();
    if (threadIdx.x < NVAL)
        partials[(size_t)threadIdx.x * nblk + blockIdx.x] = red[threadIdx.x];
}

// Shared solve tail: wave-parallel Cholesky + L^{-1} from sm[NVAL] (wave 0).
__device__ __forceinline__ void solve_tail(const float* sm, float* wm, int lane) {
    const float inv_m = 1.0f / M_ELEMS;
    const int i = lane;
    const float mu_i = (i < G16) ? sm[NPAIR + i] * inv_m : 0.f;

    float di = 0.f;
    if (i < G16) di = sm[i * (i + 1) / 2 + i] * inv_m - mu_i * mu_i + EPSV;
    float tr = di;
#pragma unroll
    for (int o = 32; o > 0; o >>= 1) tr += __shfl_xor(tr, o, 64);
    const float rtr = 1.0f / tr;

    float A[G16];
#pragma unroll
    for (int j = 0; j < G16; ++j) {
        const float mu_j = sm[NPAIR + j] * inv_m;
        const int idx = (i >= j) ? (i * (i + 1) / 2 + j) : (j * (j + 1) / 2 + i);
        float v = (i < G16) ? sm[idx] * inv_m : 0.f;
        v = v - mu_i * mu_j + ((i == j) ? EPSV : 0.f);
        A[j] = v * rtr;
    }

    float Lr[G16];
    float dinv = 0.f;
#pragma unroll
    for (int j = 0; j < G16; ++j) {
        float s = A[j];
#pragma unroll
        for (int k = 0; k < j; ++k)
            s -= Lr[k] * __shfl(Lr[k], j, 64);
        const float djj = __shfl(s, j, 64);
        const float d = sqrtf(djj);
        const float inv = 1.0f / d;
        float lij = (i == j) ? d : s * inv;
        if (i < j) lij = 0.f;
        Lr[j] = lij;
        if (i == j) dinv = inv;
    }

    float Wc[G16];
#pragma unroll
    for (int r = 0; r < G16; ++r) {
        float s = (lane == r) ? 1.f : 0.f;
#pragma unroll
        for (int k = 0; k < r; ++k)
            s -= __shfl(Lr[k], r, 64) * Wc[k];
        Wc[r] = s * __shfl(dinv, r, 64);
    }
    if (lane < G16) {
#pragma unroll
        for (int r = 0; r < G16; ++r)
            wm[r * G16 + lane] = Wc[r];
    }
}

// Pass 2 (one block, 1024 thr): unrolled reduce — compile-time NB so each
// value's 1024-wide row is read as 4 independent float4 loads per lane.
__global__ __launch_bounds__(1024) void solve_k_fast(const float* __restrict__ partials,
                                                     float* __restrict__ wm) {
    __shared__ float sm[NVAL];
    const int lane = threadIdx.x & 63;
    const int wave = threadIdx.x >> 6;
#pragma unroll 1
    for (int v = wave; v < NVAL; v += 16) {
        const float* row = partials + (size_t)v * NBLK_MAX;
        f4 a4 = {0.f, 0.f, 0.f, 0.f};
#pragma unroll
        for (int b = 0; b < NBLK_MAX / 256; ++b) {   // 4 independent 16B loads
            const f4 p = *reinterpret_cast<const f4*>(row + b * 256 + lane * 4);
            a4.x += p.x; a4.y += p.y; a4.z += p.z; a4.w += p.w;
        }
        float a = (a4.x + a4.y) + (a4.z + a4.w);
        a = wred(a);
        if (lane == 0) sm[v] = a;
    }
    __syncthreads();
    if (wave != 0) return;
    solve_tail(sm, wm, lane);
}

// Generic fallback (runtime nblk) — only used if ws can't fit 1024 partials.
__global__ __launch_bounds__(1024) void solve_k_gen(const float* __restrict__ partials,
                                                    int nblk, float* __restrict__ wm) {
    __shared__ float sm[NVAL];
    const int lane = threadIdx.x & 63;
    const int wave = threadIdx.x >> 6;
    for (int v = wave; v < NVAL; v += 16) {
        float a = 0.f;
        for (int b = lane; b < nblk; b += 64)
            a += partials[(size_t)v * nblk + b];
        a = wred(a);
        if (lane == 0) sm[v] = a;
    }
    __syncthreads();
    if (wave != 0) return;
    solve_tail(sm, wm, lane);
}

// Pass 3: out[g,:] = sum_{g2<=g} wm[g][g2] * x[g2,:]
// R4/R10 config (best known): plain loads (x is L3-resident after gram),
// NT stores (out bypasses L3, doesn't evict x). One chunk per thread.
__global__ __launch_bounds__(256, 4) void apply_k(const float* __restrict__ x,
                                                  const float* __restrict__ wm,
                                                  float* __restrict__ out) {
    __shared__ float w[G16 * G16];
    if (threadIdx.x < G16 * G16) w[threadIdx.x] = wm[threadIdx.x];
    __syncthreads();
    const int c = blockIdx.x * 256 + threadIdx.x;
    const int n = c / J4;
    const int j4 = c - n * J4;
    const size_t base = (size_t)n * (G16 * CHW) + (size_t)j4 * 4;
    f4 v[G16];
#pragma unroll
    for (int g = 0; g < G16; ++g)
        v[g] = *reinterpret_cast<const f4*>(x + base + (size_t)g * CHW);
#pragma unroll
    for (int g = 0; g < G16; ++g) {
        f4 o = {0.f, 0.f, 0.f, 0.f};
#pragma unroll
        for (int g2 = 0; g2 <= g; ++g2) {
            const float wv = w[g * G16 + g2];
            o.x = fmaf(wv, v[g2].x, o.x);
            o.y = fmaf(wv, v[g2].y, o.y);
            o.z = fmaf(wv, v[g2].z, o.z);
            o.w = fmaf(wv, v[g2].w, o.w);
        }
        __builtin_nontemporal_store(o, reinterpret_cast<f4*>(out + base + (size_t)g * CHW));
    }
}

extern "C" void kernel_launch(void* const* d_in, const int* in_sizes, int n_in,
                              void* d_out, int out_size, void* d_ws, size_t ws_size,
                              hipStream_t stream) {
    const float* x = (const float*)d_in[0];
    float* out = (float*)d_out;
    float* wm = (float*)d_ws;                 // first 256 floats
    float* partials = (float*)d_ws + 256;     // NVAL * nblk floats

    int nblk = NBLK_MAX;
    const size_t avail = (ws_size / 4 > 256) ? ((ws_size / 4 - 256) / NVAL) : 1;
    if ((size_t)nblk > avail) nblk = (int)avail;
    if (nblk < 1) nblk = 1;

    gram_k<<<nblk, 256, 0, stream>>>(x, partials, nblk);
    if (nblk == NBLK_MAX)
        solve_k_fast<<<1, 1024, 0, stream>>>(partials, wm);
    else
        solve_k_gen<<<1, 1024, 0, stream>>>(partials, nblk, wm);
    apply_k<<<NCHUNK / 256, 256, 0, stream>>>(x, wm, out);
}